// Round 6
// baseline (1449.485 us; speedup 1.0000x reference)
//
#include <hip/hip_runtime.h>

#define HID 128
#define BSH 6                 // 64 dst nodes per bucket
#define BSZ 64
#define NBMAX 1024

typedef unsigned int uint;
typedef unsigned short ushort;
typedef __attribute__((ext_vector_type(8))) short short8;
typedef __attribute__((ext_vector_type(4))) float f32x4;

__device__ __forceinline__ uint pack_bf16x2(float a, float b) {
    uint ua = __float_as_uint(a);
    ua += 0x7fffu + ((ua >> 16) & 1u);          // RNE
    uint ub = __float_as_uint(b);
    ub += 0x7fffu + ((ub >> 16) & 1u);
    return (ua >> 16) | (ub & 0xffff0000u);
}

__device__ __forceinline__ ushort bf16_of(float x) {
    uint u = __float_as_uint(x);
    u += 0x7fffu + ((u >> 16) & 1u);
    return (ushort)(u >> 16);
}

__device__ __forceinline__ float4 addbias_prelu(float4 v, float4 b, float a) {
    v.x += b.x; v.y += b.y; v.z += b.z; v.w += b.w;
    v.x = v.x >= 0.f ? v.x : a * v.x;
    v.y = v.y >= 0.f ? v.y : a * v.y;
    v.z = v.z >= 0.f ? v.z : a * v.z;
    v.w = v.w >= 0.f ? v.w : a * v.w;
    return v;
}

union FragAB { uint4 u; short8 s; };

// ---------------- W -> fragment-linear bf16 pre-pack ----------------
__global__ void w_to_frags(const float* __restrict__ W, ushort* __restrict__ Wb, int K) {
    int t = blockIdx.x * 256 + threadIdx.x;
    int total = (K / 32) * 8 * 64;
    if (t >= total) return;
    int lane = t & 63, f = t >> 6;
    int s = f >> 3, c = f & 7;
    int m = c * 16 + (lane & 15);
    int k0 = s * 32 + (lane >> 4) * 8;
    const float* wr = W + (size_t)m * K + k0;
    float4 a = *(const float4*)wr;
    float4 b = *(const float4*)(wr + 4);
    uint4 o = make_uint4(pack_bf16x2(a.x, a.y), pack_bf16x2(a.z, a.w),
                         pack_bf16x2(b.x, b.y), pack_bf16x2(b.z, b.w));
    *(uint4*)(Wb + (size_t)t * 8) = o;
}

// ---------------- MFMA GEMM: fts_bf16 = f(X) @ W^T ----------------
template <int K, bool FUSE>
__global__ __launch_bounds__(256) void gemm_mfma(
    const float* __restrict__ X, const ushort* __restrict__ Wb,
    const float* __restrict__ bias, const float* __restrict__ alpha,
    ushort* __restrict__ out, int N) {
    const int lane = threadIdx.x & 63;
    const int wid  = threadIdx.x >> 6;
    const int n0   = blockIdx.x * 64 + wid * 16;
    const int arow = n0 + (lane & 15);
    const bool okA = arow < N;
    const int kgrp = (lane >> 4) * 8;
    const float* xrow = X + (size_t)arow * K;
    const float a_ = FUSE ? alpha[0] : 0.f;

    f32x4 acc[8];
#pragma unroll
    for (int c = 0; c < 8; ++c) acc[c] = (f32x4){0.f, 0.f, 0.f, 0.f};

#pragma unroll
    for (int s = 0; s < K / 32; ++s) {
        const int k0 = s * 32 + kgrp;
        float4 va = make_float4(0.f, 0.f, 0.f, 0.f), vb = va;
        if (okA) {
            va = *(const float4*)(xrow + k0);
            vb = *(const float4*)(xrow + k0 + 4);
        }
        if (FUSE) {
            float4 ba = *(const float4*)(bias + k0);
            float4 bb = *(const float4*)(bias + k0 + 4);
            va = addbias_prelu(va, ba, a_);
            vb = addbias_prelu(vb, bb, a_);
        }
        FragAB af;
        af.u = make_uint4(pack_bf16x2(va.x, va.y), pack_bf16x2(va.z, va.w),
                          pack_bf16x2(vb.x, vb.y), pack_bf16x2(vb.z, vb.w));
#pragma unroll
        for (int c = 0; c < 8; ++c) {
            FragAB bfr;
            bfr.u = *(const uint4*)(Wb + (size_t)((s * 8 + c) * 64 + lane) * 8);
            acc[c] = __builtin_amdgcn_mfma_f32_16x16x32_bf16(af.s, bfr.s, acc[c], 0, 0, 0);
        }
    }
    const int col = lane & 15;
    const int rbase = n0 + (lane >> 4) * 4;
#pragma unroll
    for (int c = 0; c < 8; ++c) {
#pragma unroll
        for (int r = 0; r < 4; ++r) {
            int n = rbase + r;
            if (n < N) out[(size_t)n * HID + c * 16 + col] = bf16_of(acc[c][r]);
        }
    }
}

// ---------------- bucket build ----------------
__global__ __launch_bounds__(256) void bucket_hist(const int* __restrict__ dst,
                                                   int* __restrict__ ghist, int E, int NB) {
    __shared__ int h[NBMAX];
    for (int i = threadIdx.x; i < NB; i += 256) h[i] = 0;
    __syncthreads();
    int stride = gridDim.x * 256;
    for (int e = blockIdx.x * 256 + threadIdx.x; e < E; e += stride)
        atomicAdd(&h[dst[e] >> BSH], 1);
    __syncthreads();
    for (int i = threadIdx.x; i < NB; i += 256) {
        int c = h[i];
        if (c) atomicAdd(&ghist[i], c);
    }
}

__global__ __launch_bounds__(NBMAX) void bucket_scan(const int* __restrict__ ghist,
                                                     int* __restrict__ gbase,
                                                     int* __restrict__ gcur, int NB, int E) {
    __shared__ int l[NBMAX];
    int t = threadIdx.x;
    int v = (t < NB) ? ghist[t] : 0;
    l[t] = v;
    __syncthreads();
    int x = v;
    for (int o = 1; o < NBMAX; o <<= 1) {
        int y = (t >= o) ? l[t - o] : 0;
        __syncthreads();
        x += y;
        l[t] = x;
        __syncthreads();
    }
    if (t < NB) { gbase[t] = x - v; gcur[t] = x - v; }
    if (t == 0) gbase[NB] = E;
}

// stage edges grouped by bucket; packs (src | dlocal<<16, w). Requires N<=65535.
__global__ __launch_bounds__(256) void bucket_stage(
    const int* __restrict__ src, const int* __restrict__ dst,
    const float* __restrict__ w, int* __restrict__ gcur,
    int2* __restrict__ staged, int E, int NB) {
    __shared__ int lh[NBMAX], lb[NBMAX];
    for (int i = threadIdx.x; i < NB; i += 256) lh[i] = 0;
    __syncthreads();
    int chunk = (E + gridDim.x - 1) / gridDim.x;
    int c0 = blockIdx.x * chunk;
    int c1 = min(c0 + chunk, E);
    for (int e = c0 + threadIdx.x; e < c1; e += 256)
        atomicAdd(&lh[dst[e] >> BSH], 1);
    __syncthreads();
    for (int i = threadIdx.x; i < NB; i += 256) {
        int c = lh[i];
        lb[i] = c ? atomicAdd(&gcur[i], c) : 0;
        lh[i] = 0;                           // reuse as local cursor
    }
    __syncthreads();
    for (int e = c0 + threadIdx.x; e < c1; e += 256) {
        int d = dst[e];
        int b = d >> BSH;
        int slot = lb[b] + atomicAdd(&lh[b], 1);
        staged[slot] = make_int2(src[e] | ((d & (BSZ - 1)) << 16), __float_as_int(w[e]));
    }
}

// ---------------- bucketed SpMM: LDS fp32 accumulators, no global atomics ----------------
// one block per bucket (64 dst rows); wave gathers one bf16 fts row per edge.
template <bool FUSE>
__global__ __launch_bounds__(256) void bucket_gather(
    const int* __restrict__ gbase, const int2* __restrict__ staged,
    const ushort* __restrict__ fts, float* __restrict__ out,
    const float* __restrict__ bias, const float* __restrict__ alpha, int N) {
    __shared__ float acc[BSZ][HID];          // 32 KB
    const int t = threadIdx.x;
    const int b = blockIdx.x;
#pragma unroll
    for (int i = 0; i < 8; ++i)
        *(float4*)&((float*)acc)[(t + i * 256) * 4] = make_float4(0.f, 0.f, 0.f, 0.f);
    __syncthreads();

    const int lane = t & 63;
    const int wid  = t >> 6;
    int e = gbase[b] + wid;
    const int end = gbase[b + 1];

#define ROWU(m) (*((const uint*)(fts + (size_t)((m).x & 0xffff) * HID) + lane))
#define LO(r) __uint_as_float((r) << 16)
#define HI(r) __uint_as_float((r) & 0xffff0000u)

    for (; e + 12 < end; e += 16) {
        int2 m0 = staged[e], m1 = staged[e + 4], m2 = staged[e + 8], m3 = staged[e + 12];
        uint r0 = ROWU(m0), r1 = ROWU(m1), r2 = ROWU(m2), r3 = ROWU(m3);
        float w0 = __int_as_float(m0.y), w1 = __int_as_float(m1.y);
        float w2 = __int_as_float(m2.y), w3 = __int_as_float(m3.y);
        int d0 = (m0.x >> 16) & 63, d1 = (m1.x >> 16) & 63;
        int d2 = (m2.x >> 16) & 63, d3 = (m3.x >> 16) & 63;
        atomicAdd(&acc[d0][lane * 2], w0 * LO(r0));
        atomicAdd(&acc[d0][lane * 2 + 1], w0 * HI(r0));
        atomicAdd(&acc[d1][lane * 2], w1 * LO(r1));
        atomicAdd(&acc[d1][lane * 2 + 1], w1 * HI(r1));
        atomicAdd(&acc[d2][lane * 2], w2 * LO(r2));
        atomicAdd(&acc[d2][lane * 2 + 1], w2 * HI(r2));
        atomicAdd(&acc[d3][lane * 2], w3 * LO(r3));
        atomicAdd(&acc[d3][lane * 2 + 1], w3 * HI(r3));
    }
    for (; e < end; e += 4) {
        int2 m = staged[e];
        uint r = ROWU(m);
        float wt = __int_as_float(m.y);
        int d = (m.x >> 16) & 63;
        atomicAdd(&acc[d][lane * 2], wt * LO(r));
        atomicAdd(&acc[d][lane * 2 + 1], wt * HI(r));
    }
#undef ROWU
#undef LO
#undef HI
    __syncthreads();

    const int n0 = b << BSH;
    const float a = FUSE ? alpha[0] : 0.f;
#pragma unroll
    for (int i = 0; i < 32; ++i) {
        int idx = t + i * 256;
        int row = idx >> 7, col = idx & 127;
        int n = n0 + row;
        if (n < N) {
            float v = acc[row][col];
            if (FUSE) {
                v += bias[col];
                v = v >= 0.f ? v : a * v;
            }
            out[(size_t)n * HID + col] = v;
        }
    }
}

extern "C" void kernel_launch(void* const* d_in, const int* in_sizes, int n_in,
                              void* d_out, int out_size, void* d_ws, size_t ws_size,
                              hipStream_t stream) {
    const float* x  = (const float*)d_in[0];
    const int*   ei = (const int*)d_in[1];
    const float* ew = (const float*)d_in[2];
    const float* W1 = (const float*)d_in[3];
    const float* b1 = (const float*)d_in[4];
    const float* a1 = (const float*)d_in[5];
    const float* W2 = (const float*)d_in[6];
    const float* b2 = (const float*)d_in[7];
    const float* a2 = (const float*)d_in[8];
    float* out = (float*)d_out;

    int N = in_sizes[0] / 256;   // 50000 (fits in 16 bits for edge packing)
    int E = in_sizes[2];         // 800000
    const int* src = ei;
    const int* dst = ei + E;
    int NB = (N + BSZ - 1) >> BSH;   // 782

    // workspace layout
    ushort* fts    = (ushort*)d_ws;                   // N*HID bf16
    int2*   staged = (int2*)(fts + (size_t)N * HID);  // E
    ushort* Wb1    = (ushort*)(staged + E);           // 128*256
    ushort* Wb2    = Wb1 + 128 * 256;                 // 128*128
    int*    ghist  = (int*)(Wb2 + 128 * 128);         // NBMAX
    int*    gbase  = ghist + NBMAX;                   // NBMAX+1
    int*    gcur   = gbase + NBMAX + 1;               // NBMAX

    // ---- W pre-pack ----
    w_to_frags<<<16, 256, 0, stream>>>(W1, Wb1, 256);
    w_to_frags<<<8, 256, 0, stream>>>(W2, Wb2, 128);

    // ---- bucket build (replaces full CSR) ----
    hipMemsetAsync(ghist, 0, NB * sizeof(int), stream);
    bucket_hist<<<256, 256, 0, stream>>>(dst, ghist, E, NB);
    bucket_scan<<<1, NBMAX, 0, stream>>>(ghist, gbase, gcur, NB, E);
    bucket_stage<<<256, 256, 0, stream>>>(src, dst, ew, gcur, staged, E, NB);

    int gblk = (N + 63) / 64;

    // ---- layer 1 ---- (bias1+PReLU1 fused into gemm2's A-load)
    gemm_mfma<256, false><<<gblk, 256, 0, stream>>>(x, Wb1, nullptr, nullptr, fts, N);
    bucket_gather<false><<<NB, 256, 0, stream>>>(gbase, staged, fts, out, nullptr, nullptr, N);

    // ---- layer 2 ---- (bias2+PReLU2 fused into gather epilogue)
    gemm_mfma<128, true><<<gblk, 256, 0, stream>>>(out, Wb2, b1, a1, fts, N);
    bucket_gather<true><<<NB, 256, 0, stream>>>(gbase, staged, fts, out, b2, a2, N);
}

// Round 7
// 170.271 us; speedup vs baseline: 8.5128x; 8.5128x over previous
//
#include <hip/hip_runtime.h>

#define HID 128
#define BSH 6                 // 64 dst nodes per bucket
#define BSZ 64
#define NBMAX 1024

typedef unsigned int uint;
typedef unsigned short ushort;
typedef __attribute__((ext_vector_type(8))) short short8;
typedef __attribute__((ext_vector_type(4))) float f32x4;

__device__ __forceinline__ uint pack_bf16x2(float a, float b) {
    uint ua = __float_as_uint(a);
    ua += 0x7fffu + ((ua >> 16) & 1u);          // RNE
    uint ub = __float_as_uint(b);
    ub += 0x7fffu + ((ub >> 16) & 1u);
    return (ua >> 16) | (ub & 0xffff0000u);
}

__device__ __forceinline__ ushort bf16_of(float x) {
    uint u = __float_as_uint(x);
    u += 0x7fffu + ((u >> 16) & 1u);
    return (ushort)(u >> 16);
}

__device__ __forceinline__ float4 addbias_prelu(float4 v, float4 b, float a) {
    v.x += b.x; v.y += b.y; v.z += b.z; v.w += b.w;
    v.x = v.x >= 0.f ? v.x : a * v.x;
    v.y = v.y >= 0.f ? v.y : a * v.y;
    v.z = v.z >= 0.f ? v.z : a * v.z;
    v.w = v.w >= 0.f ? v.w : a * v.w;
    return v;
}

union FragAB { uint4 u; short8 s; };

// ---------------- W -> fragment-linear bf16 pre-pack ----------------
__global__ void w_to_frags(const float* __restrict__ W, ushort* __restrict__ Wb, int K) {
    int t = blockIdx.x * 256 + threadIdx.x;
    int total = (K / 32) * 8 * 64;
    if (t >= total) return;
    int lane = t & 63, f = t >> 6;
    int s = f >> 3, c = f & 7;
    int m = c * 16 + (lane & 15);
    int k0 = s * 32 + (lane >> 4) * 8;
    const float* wr = W + (size_t)m * K + k0;
    float4 a = *(const float4*)wr;
    float4 b = *(const float4*)(wr + 4);
    uint4 o = make_uint4(pack_bf16x2(a.x, a.y), pack_bf16x2(a.z, a.w),
                         pack_bf16x2(b.x, b.y), pack_bf16x2(b.z, b.w));
    *(uint4*)(Wb + (size_t)t * 8) = o;
}

// ---------------- MFMA GEMM: fts_bf16 = f(X) @ W^T ----------------
template <int K, bool FUSE>
__global__ __launch_bounds__(256) void gemm_mfma(
    const float* __restrict__ X, const ushort* __restrict__ Wb,
    const float* __restrict__ bias, const float* __restrict__ alpha,
    ushort* __restrict__ out, int N) {
    const int lane = threadIdx.x & 63;
    const int wid  = threadIdx.x >> 6;
    const int n0   = blockIdx.x * 64 + wid * 16;
    const int arow = n0 + (lane & 15);
    const bool okA = arow < N;
    const int kgrp = (lane >> 4) * 8;
    const float* xrow = X + (size_t)arow * K;
    const float a_ = FUSE ? alpha[0] : 0.f;

    f32x4 acc[8];
#pragma unroll
    for (int c = 0; c < 8; ++c) acc[c] = (f32x4){0.f, 0.f, 0.f, 0.f};

#pragma unroll
    for (int s = 0; s < K / 32; ++s) {
        const int k0 = s * 32 + kgrp;
        float4 va = make_float4(0.f, 0.f, 0.f, 0.f), vb = va;
        if (okA) {
            va = *(const float4*)(xrow + k0);
            vb = *(const float4*)(xrow + k0 + 4);
        }
        if (FUSE) {
            float4 ba = *(const float4*)(bias + k0);
            float4 bb = *(const float4*)(bias + k0 + 4);
            va = addbias_prelu(va, ba, a_);
            vb = addbias_prelu(vb, bb, a_);
        }
        FragAB af;
        af.u = make_uint4(pack_bf16x2(va.x, va.y), pack_bf16x2(va.z, va.w),
                          pack_bf16x2(vb.x, vb.y), pack_bf16x2(vb.z, vb.w));
#pragma unroll
        for (int c = 0; c < 8; ++c) {
            FragAB bfr;
            bfr.u = *(const uint4*)(Wb + (size_t)((s * 8 + c) * 64 + lane) * 8);
            acc[c] = __builtin_amdgcn_mfma_f32_16x16x32_bf16(af.s, bfr.s, acc[c], 0, 0, 0);
        }
    }
    const int col = lane & 15;
    const int rbase = n0 + (lane >> 4) * 4;
#pragma unroll
    for (int c = 0; c < 8; ++c) {
#pragma unroll
        for (int r = 0; r < 4; ++r) {
            int n = rbase + r;
            if (n < N) out[(size_t)n * HID + c * 16 + col] = bf16_of(acc[c][r]);
        }
    }
}

// ---------------- two-level CSR build ----------------
__global__ __launch_bounds__(256) void bucket_hist(const int* __restrict__ dst,
                                                   int* __restrict__ ghist, int E, int NB) {
    __shared__ int h[NBMAX];
    for (int i = threadIdx.x; i < NB; i += 256) h[i] = 0;
    __syncthreads();
    int stride = gridDim.x * 256;
    for (int e = blockIdx.x * 256 + threadIdx.x; e < E; e += stride)
        atomicAdd(&h[dst[e] >> BSH], 1);
    __syncthreads();
    for (int i = threadIdx.x; i < NB; i += 256) {
        int c = h[i];
        if (c) atomicAdd(&ghist[i], c);
    }
}

__global__ __launch_bounds__(NBMAX) void bucket_scan(const int* __restrict__ ghist,
                                                     int* __restrict__ gbase,
                                                     int* __restrict__ gcur, int NB, int E) {
    __shared__ int l[NBMAX];
    int t = threadIdx.x;
    int v = (t < NB) ? ghist[t] : 0;
    l[t] = v;
    __syncthreads();
    int x = v;
    for (int o = 1; o < NBMAX; o <<= 1) {
        int y = (t >= o) ? l[t - o] : 0;
        __syncthreads();
        x += y;
        l[t] = x;
        __syncthreads();
    }
    if (t < NB) { gbase[t] = x - v; gcur[t] = x - v; }
    if (t == 0) gbase[NB] = E;
}

// stage edges grouped by bucket; packs (src | dlocal<<16, w). Requires N<=65535.
__global__ __launch_bounds__(256) void bucket_stage(
    const int* __restrict__ src, const int* __restrict__ dst,
    const float* __restrict__ w, int* __restrict__ gcur,
    int2* __restrict__ staged, int E, int NB) {
    __shared__ int lh[NBMAX], lb[NBMAX];
    for (int i = threadIdx.x; i < NB; i += 256) lh[i] = 0;
    __syncthreads();
    int chunk = (E + gridDim.x - 1) / gridDim.x;
    int c0 = blockIdx.x * chunk;
    int c1 = min(c0 + chunk, E);
    for (int e = c0 + threadIdx.x; e < c1; e += 256)
        atomicAdd(&lh[dst[e] >> BSH], 1);
    __syncthreads();
    for (int i = threadIdx.x; i < NB; i += 256) {
        int c = lh[i];
        lb[i] = c ? atomicAdd(&gcur[i], c) : 0;
        lh[i] = 0;                           // reuse as local cursor
    }
    __syncthreads();
    for (int e = c0 + threadIdx.x; e < c1; e += 256) {
        int d = dst[e];
        int b = d >> BSH;
        int slot = lb[b] + atomicAdd(&lh[b], 1);
        staged[slot] = make_int2(src[e] | ((d & (BSZ - 1)) << 16), __float_as_int(w[e]));
    }
}

// one block per bucket: sort the bucket's staged segment by local node, write
// per-node CSR edges (contiguous 8KB window -> single-XCD full-line writes)
// and the per-node offsets.
__global__ __launch_bounds__(256) void node_sort(
    const int* __restrict__ gbase, const int2* __restrict__ staged,
    int2* __restrict__ csr, int* __restrict__ off, int N) {
    __shared__ int hist[BSZ];
    __shared__ int cur[BSZ];
    const int b = blockIdx.x;
    const int s0 = gbase[b], s1 = gbase[b + 1];
    const int t = threadIdx.x;
    if (t < BSZ) hist[t] = 0;
    __syncthreads();
    for (int e = s0 + t; e < s1; e += 256)
        atomicAdd(&hist[(staged[e].x >> 16) & (BSZ - 1)], 1);
    __syncthreads();
    if (t < BSZ) {                         // threads 0..63 = wave 0: shfl scan
        int x = hist[t];
        int incl = x;
#pragma unroll
        for (int o = 1; o < BSZ; o <<= 1) {
            int y = __shfl_up(incl, o, BSZ);
            if (t >= o) incl += y;
        }
        int excl = incl - x;
        cur[t] = excl;
        int n = (b << BSH) + t;
        if (n <= N) off[n] = s0 + excl;
    }
    __syncthreads();
    for (int e = s0 + t; e < s1; e += 256) {
        int2 m = staged[e];
        int d = (m.x >> 16) & (BSZ - 1);
        int p = atomicAdd(&cur[d], 1);
        csr[s0 + p] = m;
    }
}

// ---------------- pull-mode SpMM over bf16 features (register acc) ----------------
__global__ __launch_bounds__(256) void csr_gather_bf16(
    const int* __restrict__ off, const int2* __restrict__ edges,
    const ushort* __restrict__ fts, float* __restrict__ out,
    const float* __restrict__ bias, const float* __restrict__ alpha, int N) {
    int d = blockIdx.x * 4 + (threadIdx.x >> 6);
    if (d >= N) return;
    int lane = threadIdx.x & 63;
    int p = off[d], end = off[d + 1];
    float acc0 = 0.f, acc1 = 0.f;

#define ROWU(e) (*((const uint*)(fts + (size_t)((e).x & 0xffff) * HID) + lane))
#define LO(r) __uint_as_float((r) << 16)
#define HI(r) __uint_as_float((r) & 0xffff0000u)

    for (; p + 3 < end; p += 4) {
        int2 e0 = edges[p], e1 = edges[p + 1], e2 = edges[p + 2], e3 = edges[p + 3];
        uint r0 = ROWU(e0), r1 = ROWU(e1), r2 = ROWU(e2), r3 = ROWU(e3);
        float w0 = __int_as_float(e0.y), w1 = __int_as_float(e1.y);
        float w2 = __int_as_float(e2.y), w3 = __int_as_float(e3.y);
        acc0 += w0 * LO(r0) + w1 * LO(r1) + w2 * LO(r2) + w3 * LO(r3);
        acc1 += w0 * HI(r0) + w1 * HI(r1) + w2 * HI(r2) + w3 * HI(r3);
    }
    for (; p < end; ++p) {
        int2 e = edges[p];
        uint r = ROWU(e);
        float wt = __int_as_float(e.y);
        acc0 += wt * LO(r);
        acc1 += wt * HI(r);
    }
#undef ROWU
#undef LO
#undef HI

    if (bias != nullptr) {
        float a = alpha[0];
        acc0 += bias[lane * 2 + 0];
        acc1 += bias[lane * 2 + 1];
        acc0 = acc0 >= 0.f ? acc0 : a * acc0;
        acc1 = acc1 >= 0.f ? acc1 : a * acc1;
    }
    *(float2*)&out[(size_t)d * HID + lane * 2] = make_float2(acc0, acc1);
}

extern "C" void kernel_launch(void* const* d_in, const int* in_sizes, int n_in,
                              void* d_out, int out_size, void* d_ws, size_t ws_size,
                              hipStream_t stream) {
    const float* x  = (const float*)d_in[0];
    const int*   ei = (const int*)d_in[1];
    const float* ew = (const float*)d_in[2];
    const float* W1 = (const float*)d_in[3];
    const float* b1 = (const float*)d_in[4];
    const float* a1 = (const float*)d_in[5];
    const float* W2 = (const float*)d_in[6];
    const float* b2 = (const float*)d_in[7];
    const float* a2 = (const float*)d_in[8];
    float* out = (float*)d_out;

    int N = in_sizes[0] / 256;   // 50000 (fits in 16 bits for edge packing)
    int E = in_sizes[2];         // 800000
    const int* src = ei;
    const int* dst = ei + E;
    int NB = (N + BSZ - 1) >> BSH;   // 782

    // workspace layout
    ushort* fts    = (ushort*)d_ws;                   // N*HID bf16
    int2*   staged = (int2*)(fts + (size_t)N * HID);  // E
    int2*   csr    = staged + E;                      // E
    ushort* Wb1    = (ushort*)(csr + E);              // 128*256
    ushort* Wb2    = Wb1 + 128 * 256;                 // 128*128
    int*    ghist  = (int*)(Wb2 + 128 * 128);         // NBMAX
    int*    gbase  = ghist + NBMAX;                   // NBMAX+1
    int*    gcur   = gbase + NBMAX + 1;               // NBMAX
    int*    off    = gcur + NBMAX;                    // N+1

    // ---- W pre-pack ----
    w_to_frags<<<16, 256, 0, stream>>>(W1, Wb1, 256);
    w_to_frags<<<8, 256, 0, stream>>>(W2, Wb2, 128);

    // ---- two-level CSR build ----
    hipMemsetAsync(ghist, 0, NB * sizeof(int), stream);
    bucket_hist<<<256, 256, 0, stream>>>(dst, ghist, E, NB);
    bucket_scan<<<1, NBMAX, 0, stream>>>(ghist, gbase, gcur, NB, E);
    bucket_stage<<<256, 256, 0, stream>>>(src, dst, ew, gcur, staged, E, NB);
    node_sort<<<NB, 256, 0, stream>>>(gbase, staged, csr, off, N);

    int gblk = (N + 63) / 64;
    int ggrid = (N + 3) / 4;

    // ---- layer 1 ---- (bias1+PReLU1 fused into gemm2's A-load)
    gemm_mfma<256, false><<<gblk, 256, 0, stream>>>(x, Wb1, nullptr, nullptr, fts, N);
    csr_gather_bf16<<<ggrid, 256, 0, stream>>>(off, csr, fts, out, nullptr, nullptr, N);

    // ---- layer 2 ---- (bias2+PReLU2 fused into gather epilogue)
    gemm_mfma<128, true><<<gblk, 256, 0, stream>>>(out, Wb2, b1, a1, fts, N);
    csr_gather_bf16<<<ggrid, 256, 0, stream>>>(off, csr, fts, out, b2, a2, N);
}

// Round 8
// 157.636 us; speedup vs baseline: 9.1951x; 1.0802x over previous
//
#include <hip/hip_runtime.h>

#define HID 128
#define BSH 6                 // 64 dst nodes per bucket
#define BSZ 64
#define NBMAX 1024

typedef unsigned int uint;
typedef unsigned short ushort;
typedef __attribute__((ext_vector_type(8))) short short8;
typedef __attribute__((ext_vector_type(4))) float f32x4;

__device__ __forceinline__ uint pack_bf16x2(float a, float b) {
    uint ua = __float_as_uint(a);
    ua += 0x7fffu + ((ua >> 16) & 1u);          // RNE
    uint ub = __float_as_uint(b);
    ub += 0x7fffu + ((ub >> 16) & 1u);
    return (ua >> 16) | (ub & 0xffff0000u);
}

__device__ __forceinline__ ushort bf16_of(float x) {
    uint u = __float_as_uint(x);
    u += 0x7fffu + ((u >> 16) & 1u);
    return (ushort)(u >> 16);
}

union FragAB { uint4 u; short8 s; };

// ---------------- W pre-pack (both layers) + ghist zero, one launch ----------------
// blocks 0..15: W1 (K=256), 16..23: W2 (K=128), block 24: zero ghist
__global__ __launch_bounds__(256) void w_to_frags_both(
    const float* __restrict__ W1, const float* __restrict__ W2,
    ushort* __restrict__ Wb1, ushort* __restrict__ Wb2, int* __restrict__ ghist) {
    int blk = blockIdx.x;
    if (blk == 24) {
        ((int4*)ghist)[threadIdx.x] = make_int4(0, 0, 0, 0);   // NBMAX ints
        return;
    }
    const float* W = (blk < 16) ? W1 : W2;
    ushort* Wb = (blk < 16) ? Wb1 : Wb2;
    int K = (blk < 16) ? 256 : 128;
    int t = ((blk < 16) ? blk : blk - 16) * 256 + threadIdx.x;
    int lane = t & 63, f = t >> 6;
    int s = f >> 3, c = f & 7;
    int m = c * 16 + (lane & 15);
    int k0 = s * 32 + (lane >> 4) * 8;
    const float* wr = W + (size_t)m * K + k0;
    float4 a = *(const float4*)wr;
    float4 b = *(const float4*)(wr + 4);
    uint4 o = make_uint4(pack_bf16x2(a.x, a.y), pack_bf16x2(a.z, a.w),
                         pack_bf16x2(b.x, b.y), pack_bf16x2(b.z, b.w));
    *(uint4*)(Wb + (size_t)t * 8) = o;
}

// ---------------- MFMA GEMM: fts_bf16 = X @ W^T (X fp32 or bf16) ----------------
template <int K, bool ABF16>
__global__ __launch_bounds__(256) void gemm_mfma(
    const void* __restrict__ Xv, const ushort* __restrict__ Wb,
    ushort* __restrict__ out, int N) {
    const int lane = threadIdx.x & 63;
    const int wid  = threadIdx.x >> 6;
    const int n0   = blockIdx.x * 64 + wid * 16;
    const int arow = n0 + (lane & 15);
    const bool okA = arow < N;
    const int kgrp = (lane >> 4) * 8;
    const float*  xrow_f = (const float*)Xv + (size_t)arow * K;
    const ushort* xrow_h = (const ushort*)Xv + (size_t)arow * K;

    f32x4 acc[8];
#pragma unroll
    for (int c = 0; c < 8; ++c) acc[c] = (f32x4){0.f, 0.f, 0.f, 0.f};

#pragma unroll
    for (int s = 0; s < K / 32; ++s) {
        const int k0 = s * 32 + kgrp;
        FragAB af;
        if (ABF16) {
            af.u = okA ? *(const uint4*)(xrow_h + k0) : make_uint4(0, 0, 0, 0);
        } else {
            float4 va = make_float4(0.f, 0.f, 0.f, 0.f), vb = va;
            if (okA) {
                va = *(const float4*)(xrow_f + k0);
                vb = *(const float4*)(xrow_f + k0 + 4);
            }
            af.u = make_uint4(pack_bf16x2(va.x, va.y), pack_bf16x2(va.z, va.w),
                              pack_bf16x2(vb.x, vb.y), pack_bf16x2(vb.z, vb.w));
        }
#pragma unroll
        for (int c = 0; c < 8; ++c) {
            FragAB bfr;
            bfr.u = *(const uint4*)(Wb + (size_t)((s * 8 + c) * 64 + lane) * 8);
            acc[c] = __builtin_amdgcn_mfma_f32_16x16x32_bf16(af.s, bfr.s, acc[c], 0, 0, 0);
        }
    }
    const int col = lane & 15;
    const int rbase = n0 + (lane >> 4) * 4;
#pragma unroll
    for (int c = 0; c < 8; ++c) {
#pragma unroll
        for (int r = 0; r < 4; ++r) {
            int n = rbase + r;
            if (n < N) out[(size_t)n * HID + c * 16 + col] = bf16_of(acc[c][r]);
        }
    }
}

// ---------------- two-level CSR build ----------------
__global__ __launch_bounds__(256) void bucket_hist(const int* __restrict__ dst,
                                                   int* __restrict__ ghist, int E, int NB) {
    __shared__ int h[NBMAX];
    for (int i = threadIdx.x; i < NB; i += 256) h[i] = 0;
    __syncthreads();
    int stride = gridDim.x * 256;
    for (int e = blockIdx.x * 256 + threadIdx.x; e < E; e += stride)
        atomicAdd(&h[dst[e] >> BSH], 1);
    __syncthreads();
    for (int i = threadIdx.x; i < NB; i += 256) {
        int c = h[i];
        if (c) atomicAdd(&ghist[i], c);
    }
}

__global__ __launch_bounds__(NBMAX) void bucket_scan(const int* __restrict__ ghist,
                                                     int* __restrict__ gbase,
                                                     int* __restrict__ gcur, int NB, int E) {
    __shared__ int l[NBMAX];
    int t = threadIdx.x;
    int v = (t < NB) ? ghist[t] : 0;
    l[t] = v;
    __syncthreads();
    int x = v;
    for (int o = 1; o < NBMAX; o <<= 1) {
        int y = (t >= o) ? l[t - o] : 0;
        __syncthreads();
        x += y;
        l[t] = x;
        __syncthreads();
    }
    if (t < NB) { gbase[t] = x - v; gcur[t] = x - v; }
    if (t == 0) gbase[NB] = E;
}

// stage edges grouped by bucket; packs (src | dlocal<<16, w). Requires N<=65535.
__global__ __launch_bounds__(256) void bucket_stage(
    const int* __restrict__ src, const int* __restrict__ dst,
    const float* __restrict__ w, int* __restrict__ gcur,
    int2* __restrict__ staged, int E, int NB) {
    __shared__ int lh[NBMAX], lb[NBMAX];
    for (int i = threadIdx.x; i < NB; i += 256) lh[i] = 0;
    __syncthreads();
    int chunk = (E + gridDim.x - 1) / gridDim.x;
    int c0 = blockIdx.x * chunk;
    int c1 = min(c0 + chunk, E);
    for (int e = c0 + threadIdx.x; e < c1; e += 256)
        atomicAdd(&lh[dst[e] >> BSH], 1);
    __syncthreads();
    for (int i = threadIdx.x; i < NB; i += 256) {
        int c = lh[i];
        lb[i] = c ? atomicAdd(&gcur[i], c) : 0;
        lh[i] = 0;                           // reuse as local cursor
    }
    __syncthreads();
    for (int e = c0 + threadIdx.x; e < c1; e += 256) {
        int d = dst[e];
        int b = d >> BSH;
        int slot = lb[b] + atomicAdd(&lh[b], 1);
        staged[slot] = make_int2(src[e] | ((d & (BSZ - 1)) << 16), __float_as_int(w[e]));
    }
}

// one block per bucket: sort bucket's segment by local node into csr; emit off[].
__global__ __launch_bounds__(256) void node_sort(
    const int* __restrict__ gbase, const int2* __restrict__ staged,
    int2* __restrict__ csr, int* __restrict__ off, int N) {
    __shared__ int hist[BSZ];
    __shared__ int cur[BSZ];
    const int b = blockIdx.x;
    const int s0 = gbase[b], s1 = gbase[b + 1];
    const int t = threadIdx.x;
    if (t < BSZ) hist[t] = 0;
    __syncthreads();
    for (int e = s0 + t; e < s1; e += 256)
        atomicAdd(&hist[(staged[e].x >> 16) & (BSZ - 1)], 1);
    __syncthreads();
    if (t < BSZ) {                         // wave 0: shfl inclusive scan
        int x = hist[t];
        int incl = x;
#pragma unroll
        for (int o = 1; o < BSZ; o <<= 1) {
            int y = __shfl_up(incl, o, BSZ);
            if (t >= o) incl += y;
        }
        int excl = incl - x;
        cur[t] = excl;
        int n = (b << BSH) + t;
        if (n <= N) off[n] = s0 + excl;
    }
    __syncthreads();
    for (int e = s0 + t; e < s1; e += 256) {
        int2 m = staged[e];
        int d = (m.x >> 16) & (BSZ - 1);
        int p = atomicAdd(&cur[d], 1);
        csr[s0 + p] = m;
    }
}

// ---------------- pull-mode SpMM over bf16 features (register acc) ----------------
// one wave per dst node; always applies bias+PReLU; OUTBF16 selects output type.
template <bool OUTBF16>
__global__ __launch_bounds__(256) void csr_gather_bf16(
    const int* __restrict__ off, const int2* __restrict__ edges,
    const ushort* __restrict__ fts, void* __restrict__ outv,
    const float* __restrict__ bias, const float* __restrict__ alpha, int N) {
    int d = blockIdx.x * 4 + (threadIdx.x >> 6);
    if (d >= N) return;
    int lane = threadIdx.x & 63;
    int p = off[d], end = off[d + 1];
    float acc0 = 0.f, acc1 = 0.f;

#define ROWU(e) (*((const uint*)(fts + (size_t)((e).x & 0xffff) * HID) + lane))
#define LO(r) __uint_as_float((r) << 16)
#define HI(r) __uint_as_float((r) & 0xffff0000u)

    for (; p + 7 < end; p += 8) {
        int2 e[8];
        uint r[8];
#pragma unroll
        for (int i = 0; i < 8; ++i) e[i] = edges[p + i];
#pragma unroll
        for (int i = 0; i < 8; ++i) r[i] = ROWU(e[i]);
#pragma unroll
        for (int i = 0; i < 8; ++i) {
            float wt = __int_as_float(e[i].y);
            acc0 += wt * LO(r[i]);
            acc1 += wt * HI(r[i]);
        }
    }
    for (; p + 3 < end; p += 4) {
        int2 e0 = edges[p], e1 = edges[p + 1], e2 = edges[p + 2], e3 = edges[p + 3];
        uint r0 = ROWU(e0), r1 = ROWU(e1), r2 = ROWU(e2), r3 = ROWU(e3);
        float w0 = __int_as_float(e0.y), w1 = __int_as_float(e1.y);
        float w2 = __int_as_float(e2.y), w3 = __int_as_float(e3.y);
        acc0 += w0 * LO(r0) + w1 * LO(r1) + w2 * LO(r2) + w3 * LO(r3);
        acc1 += w0 * HI(r0) + w1 * HI(r1) + w2 * HI(r2) + w3 * HI(r3);
    }
    for (; p < end; ++p) {
        int2 e = edges[p];
        uint r = ROWU(e);
        float wt = __int_as_float(e.y);
        acc0 += wt * LO(r);
        acc1 += wt * HI(r);
    }
#undef ROWU
#undef LO
#undef HI

    float a = alpha[0];
    acc0 += bias[lane * 2 + 0];
    acc1 += bias[lane * 2 + 1];
    acc0 = acc0 >= 0.f ? acc0 : a * acc0;
    acc1 = acc1 >= 0.f ? acc1 : a * acc1;
    if (OUTBF16) {
        ((uint*)outv)[(size_t)d * (HID / 2) + lane] = pack_bf16x2(acc0, acc1);
    } else {
        *(float2*)&((float*)outv)[(size_t)d * HID + lane * 2] = make_float2(acc0, acc1);
    }
}

extern "C" void kernel_launch(void* const* d_in, const int* in_sizes, int n_in,
                              void* d_out, int out_size, void* d_ws, size_t ws_size,
                              hipStream_t stream) {
    const float* x  = (const float*)d_in[0];
    const int*   ei = (const int*)d_in[1];
    const float* ew = (const float*)d_in[2];
    const float* W1 = (const float*)d_in[3];
    const float* b1 = (const float*)d_in[4];
    const float* a1 = (const float*)d_in[5];
    const float* W2 = (const float*)d_in[6];
    const float* b2 = (const float*)d_in[7];
    const float* a2 = (const float*)d_in[8];
    float* out = (float*)d_out;

    int N = in_sizes[0] / 256;   // 50000 (fits in 16 bits for edge packing)
    int E = in_sizes[2];         // 800000
    const int* src = ei;
    const int* dst = ei + E;
    int NB = (N + BSZ - 1) >> BSH;   // 782

    // workspace layout
    ushort* fts    = (ushort*)d_ws;                   // N*HID bf16
    ushort* agg    = fts + (size_t)N * HID;           // N*HID bf16
    int2*   staged = (int2*)(agg + (size_t)N * HID);  // E
    int2*   csr    = staged + E;                      // E
    ushort* Wb1    = (ushort*)(csr + E);              // 128*256
    ushort* Wb2    = Wb1 + 128 * 256;                 // 128*128
    int*    ghist  = (int*)(Wb2 + 128 * 128);         // NBMAX
    int*    gbase  = ghist + NBMAX;                   // NBMAX+1
    int*    gcur   = gbase + NBMAX + 1;               // NBMAX
    int*    off    = gcur + NBMAX;                    // N+1

    // ---- W pre-pack + ghist zero (one launch) ----
    w_to_frags_both<<<25, 256, 0, stream>>>(W1, W2, Wb1, Wb2, ghist);

    // ---- two-level CSR build ----
    bucket_hist<<<256, 256, 0, stream>>>(dst, ghist, E, NB);
    bucket_scan<<<1, NBMAX, 0, stream>>>(ghist, gbase, gcur, NB, E);
    bucket_stage<<<128, 256, 0, stream>>>(src, dst, ew, gcur, staged, E, NB);
    node_sort<<<NB, 256, 0, stream>>>(gbase, staged, csr, off, N);

    int gblk = (N + 63) / 64;
    int ggrid = (N + 3) / 4;

    // ---- layer 1 ---- (bias1+PReLU1 fused into gather1 epilogue, bf16 out)
    gemm_mfma<256, false><<<gblk, 256, 0, stream>>>(x, Wb1, fts, N);
    csr_gather_bf16<true><<<ggrid, 256, 0, stream>>>(off, csr, fts, agg, b1, a1, N);

    // ---- layer 2 ---- (A is bf16; bias2+PReLU2 fused into gather2 epilogue)
    gemm_mfma<128, true><<<gblk, 256, 0, stream>>>(agg, Wb2, fts, N);
    csr_gather_bf16<false><<<ggrid, 256, 0, stream>>>(off, csr, fts, out, b2, a2, N);
}

// Round 10
// 152.955 us; speedup vs baseline: 9.4765x; 1.0306x over previous
//
#include <hip/hip_runtime.h>

#define HID 128
#define BSH 6                 // 64 dst nodes per bucket
#define BSZ 64
#define NBMAX 1024

typedef unsigned int uint;
typedef unsigned short ushort;
typedef __attribute__((ext_vector_type(8))) short short8;
typedef __attribute__((ext_vector_type(4))) float f32x4;

__device__ __forceinline__ uint pack_bf16x2(float a, float b) {
    uint ua = __float_as_uint(a);
    ua += 0x7fffu + ((ua >> 16) & 1u);          // RNE
    uint ub = __float_as_uint(b);
    ub += 0x7fffu + ((ub >> 16) & 1u);
    return (ua >> 16) | (ub & 0xffff0000u);
}

__device__ __forceinline__ ushort bf16_of(float x) {
    uint u = __float_as_uint(x);
    u += 0x7fffu + ((u >> 16) & 1u);
    return (ushort)(u >> 16);
}

union FragAB { uint4 u; short8 s; };

// ---------------- W pre-pack (both layers) + ghist zero, one launch ----------------
__global__ __launch_bounds__(256) void w_to_frags_both(
    const float* __restrict__ W1, const float* __restrict__ W2,
    ushort* __restrict__ Wb1, ushort* __restrict__ Wb2, int* __restrict__ ghist) {
    int blk = blockIdx.x;
    if (blk == 24) {
        ((int4*)ghist)[threadIdx.x] = make_int4(0, 0, 0, 0);   // NBMAX ints
        return;
    }
    const float* W = (blk < 16) ? W1 : W2;
    ushort* Wb = (blk < 16) ? Wb1 : Wb2;
    int K = (blk < 16) ? 256 : 128;
    int t = ((blk < 16) ? blk : blk - 16) * 256 + threadIdx.x;
    int lane = t & 63, f = t >> 6;
    int s = f >> 3, c = f & 7;
    int m = c * 16 + (lane & 15);
    int k0 = s * 32 + (lane >> 4) * 8;
    const float* wr = W + (size_t)m * K + k0;
    float4 a = *(const float4*)wr;
    float4 b = *(const float4*)(wr + 4);
    uint4 o = make_uint4(pack_bf16x2(a.x, a.y), pack_bf16x2(a.z, a.w),
                         pack_bf16x2(b.x, b.y), pack_bf16x2(b.z, b.w));
    *(uint4*)(Wb + (size_t)t * 8) = o;
}

// ---------------- MFMA GEMM: fts_bf16 = X @ W^T (X fp32 or bf16) ----------------
// 4 waves/block; each wave computes TWO 16-row tiles sharing each B-frag load
// (halves Wb L2 traffic, doubles MFMA per issue). Block covers 128 rows.
template <int K, bool ABF16>
__device__ __forceinline__ FragAB load_afrag(const void* __restrict__ Xv, int row,
                                             int k0, bool ok) {
    FragAB af;
    if (ABF16) {
        af.u = ok ? *(const uint4*)((const ushort*)Xv + (size_t)row * K + k0)
                  : make_uint4(0, 0, 0, 0);
    } else {
        float4 va = make_float4(0.f, 0.f, 0.f, 0.f), vb = va;
        if (ok) {
            const float* xr = (const float*)Xv + (size_t)row * K + k0;
            va = *(const float4*)xr;
            vb = *(const float4*)(xr + 4);
        }
        af.u = make_uint4(pack_bf16x2(va.x, va.y), pack_bf16x2(va.z, va.w),
                          pack_bf16x2(vb.x, vb.y), pack_bf16x2(vb.z, vb.w));
    }
    return af;
}

template <int K, bool ABF16>
__global__ __launch_bounds__(256) void gemm_mfma(
    const void* __restrict__ Xv, const ushort* __restrict__ Wb,
    ushort* __restrict__ out, int N) {
    const int lane = threadIdx.x & 63;
    const int wid  = threadIdx.x >> 6;
    const int n0   = blockIdx.x * 128 + wid * 32;
    const int r0 = n0 + (lane & 15);
    const int r1 = r0 + 16;
    const bool ok0 = r0 < N, ok1 = r1 < N;
    const int kgrp = (lane >> 4) * 8;

    f32x4 acc0[8], acc1[8];
#pragma unroll
    for (int c = 0; c < 8; ++c) {
        acc0[c] = (f32x4){0.f, 0.f, 0.f, 0.f};
        acc1[c] = (f32x4){0.f, 0.f, 0.f, 0.f};
    }

#pragma unroll
    for (int s = 0; s < K / 32; ++s) {
        const int k0 = s * 32 + kgrp;
        FragAB a0 = load_afrag<K, ABF16>(Xv, r0, k0, ok0);
        FragAB a1 = load_afrag<K, ABF16>(Xv, r1, k0, ok1);
#pragma unroll
        for (int c = 0; c < 8; ++c) {
            FragAB bfr;
            bfr.u = *(const uint4*)(Wb + (size_t)((s * 8 + c) * 64 + lane) * 8);
            acc0[c] = __builtin_amdgcn_mfma_f32_16x16x32_bf16(a0.s, bfr.s, acc0[c], 0, 0, 0);
            acc1[c] = __builtin_amdgcn_mfma_f32_16x16x32_bf16(a1.s, bfr.s, acc1[c], 0, 0, 0);
        }
    }
    const int col = lane & 15;
    const int rb0 = n0 + (lane >> 4) * 4;
#pragma unroll
    for (int c = 0; c < 8; ++c) {
#pragma unroll
        for (int r = 0; r < 4; ++r) {
            int na = rb0 + r;
            if (na < N) out[(size_t)na * HID + c * 16 + col] = bf16_of(acc0[c][r]);
            int nb = na + 16;
            if (nb < N) out[(size_t)nb * HID + c * 16 + col] = bf16_of(acc1[c][r]);
        }
    }
}

// ---------------- two-level CSR build ----------------
__global__ __launch_bounds__(256) void bucket_hist(const int* __restrict__ dst,
                                                   int* __restrict__ ghist, int E, int NB) {
    __shared__ int h[NBMAX];
    for (int i = threadIdx.x; i < NB; i += 256) h[i] = 0;
    __syncthreads();
    int stride = gridDim.x * 256;
    for (int e = blockIdx.x * 256 + threadIdx.x; e < E; e += stride)
        atomicAdd(&h[dst[e] >> BSH], 1);
    __syncthreads();
    for (int i = threadIdx.x; i < NB; i += 256) {
        int c = h[i];
        if (c) atomicAdd(&ghist[i], c);
    }
}

__global__ __launch_bounds__(NBMAX) void bucket_scan(const int* __restrict__ ghist,
                                                     int* __restrict__ gbase,
                                                     int* __restrict__ gcur, int NB, int E) {
    __shared__ int l[NBMAX];
    int t = threadIdx.x;
    int v = (t < NB) ? ghist[t] : 0;
    l[t] = v;
    __syncthreads();
    int x = v;
    for (int o = 1; o < NBMAX; o <<= 1) {
        int y = (t >= o) ? l[t - o] : 0;
        __syncthreads();
        x += y;
        l[t] = x;
        __syncthreads();
    }
    if (t < NB) { gbase[t] = x - v; gcur[t] = x - v; }
    if (t == 0) gbase[NB] = E;
}

// stage edges grouped by bucket; packs (src | dlocal<<16, w). Requires N<=65535.
__global__ __launch_bounds__(256) void bucket_stage(
    const int* __restrict__ src, const int* __restrict__ dst,
    const float* __restrict__ w, int* __restrict__ gcur,
    int2* __restrict__ staged, int E, int NB) {
    __shared__ int lh[NBMAX], lb[NBMAX];
    for (int i = threadIdx.x; i < NB; i += 256) lh[i] = 0;
    __syncthreads();
    int chunk = (E + gridDim.x - 1) / gridDim.x;
    int c0 = blockIdx.x * chunk;
    int c1 = min(c0 + chunk, E);
    for (int e = c0 + threadIdx.x; e < c1; e += 256)
        atomicAdd(&lh[dst[e] >> BSH], 1);
    __syncthreads();
    for (int i = threadIdx.x; i < NB; i += 256) {
        int c = lh[i];
        lb[i] = c ? atomicAdd(&gcur[i], c) : 0;
        lh[i] = 0;                           // reuse as local cursor
    }
    __syncthreads();
    for (int e = c0 + threadIdx.x; e < c1; e += 256) {
        int d = dst[e];
        int b = d >> BSH;
        int slot = lb[b] + atomicAdd(&lh[b], 1);
        staged[slot] = make_int2(src[e] | ((d & (BSZ - 1)) << 16), __float_as_int(w[e]));
    }
}

// one block per bucket: sort bucket's segment by local node into csr; emit off[].
__global__ __launch_bounds__(256) void node_sort(
    const int* __restrict__ gbase, const int2* __restrict__ staged,
    int2* __restrict__ csr, int* __restrict__ off, int N) {
    __shared__ int hist[BSZ];
    __shared__ int cur[BSZ];
    const int b = blockIdx.x;
    const int s0 = gbase[b], s1 = gbase[b + 1];
    const int t = threadIdx.x;
    if (t < BSZ) hist[t] = 0;
    __syncthreads();
    for (int e = s0 + t; e < s1; e += 256)
        atomicAdd(&hist[(staged[e].x >> 16) & (BSZ - 1)], 1);
    __syncthreads();
    if (t < BSZ) {                         // wave 0: shfl inclusive scan
        int x = hist[t];
        int incl = x;
#pragma unroll
        for (int o = 1; o < BSZ; o <<= 1) {
            int y = __shfl_up(incl, o, BSZ);
            if (t >= o) incl += y;
        }
        int excl = incl - x;
        cur[t] = excl;
        int n = (b << BSH) + t;
        if (n <= N) off[n] = s0 + excl;
    }
    __syncthreads();
    for (int e = s0 + t; e < s1; e += 256) {
        int2 m = staged[e];
        int d = (m.x >> 16) & (BSZ - 1);
        int p = atomicAdd(&cur[d], 1);
        csr[s0 + p] = m;
    }
}

// ---------------- pull-mode SpMM over bf16 features, lane-split rows ----------------
// one wave per dst node. Lanes split 4 ways: group g (=lane>>4) owns edge slot g;
// the 16 lanes of a group fetch that edge's full 256B row at 16B/lane. One VMEM
// instruction = 4 edges' rows (1KB in flight). Butterfly-reduce groups at the end.
template <bool OUTBF16>
__global__ __launch_bounds__(256) void csr_gather_bf16(
    const int* __restrict__ off, const int2* __restrict__ edges,
    const ushort* __restrict__ fts, void* __restrict__ outv,
    const float* __restrict__ bias, const float* __restrict__ alpha, int N) {
    int d = blockIdx.x * 4 + (threadIdx.x >> 6);
    if (d >= N) return;
    const int lane = threadIdx.x & 63;
    const int g = lane >> 4;        // edge slot within 4-edge batch
    const int sub = lane & 15;      // col block: cols sub*8 .. sub*8+7
    int p = off[d];
    const int end = off[d + 1];
    float acc[8];
#pragma unroll
    for (int j = 0; j < 8; ++j) acc[j] = 0.f;

#define LOBITS(u_) __uint_as_float((u_) << 16)
#define HIBITS(u_) __uint_as_float((u_) & 0xffff0000u)
#define ACC8(R_, W_)                                              \
    do {                                                          \
        acc[0] += (W_) * LOBITS((R_).x); acc[1] += (W_) * HIBITS((R_).x); \
        acc[2] += (W_) * LOBITS((R_).y); acc[3] += (W_) * HIBITS((R_).y); \
        acc[4] += (W_) * LOBITS((R_).z); acc[5] += (W_) * HIBITS((R_).z); \
        acc[6] += (W_) * LOBITS((R_).w); acc[7] += (W_) * HIBITS((R_).w); \
    } while (0)

    for (; p + 8 <= end; p += 8) {                 // 8 edges in flight (2KB)
        int2 ma = edges[p + g];
        int2 mb = edges[p + 4 + g];
        uint4 ra = *(const uint4*)(fts + (size_t)(ma.x & 0xffff) * HID + sub * 8);
        uint4 rb = *(const uint4*)(fts + (size_t)(mb.x & 0xffff) * HID + sub * 8);
        float wa = __int_as_float(ma.y), wb = __int_as_float(mb.y);
        ACC8(ra, wa);
        ACC8(rb, wb);
    }
    for (; p < end; p += 4) {                      // masked 4-edge tail
        int i = p + g;
        int2 m = edges[(i < end) ? i : (end - 1)];
        float wt = (i < end) ? __int_as_float(m.y) : 0.f;
        uint4 r = *(const uint4*)(fts + (size_t)(m.x & 0xffff) * HID + sub * 8);
        ACC8(r, wt);
    }
#undef ACC8
#undef LOBITS
#undef HIBITS

#pragma unroll
    for (int j = 0; j < 8; ++j) {                  // fold the 4 edge-groups
        acc[j] += __shfl_xor(acc[j], 16);
        acc[j] += __shfl_xor(acc[j], 32);
    }

    const float a = alpha[0];
#pragma unroll
    for (int j = 0; j < 8; ++j) {
        float v = acc[j] + bias[sub * 8 + j];
        acc[j] = v >= 0.f ? v : a * v;
    }
    if (g == 0) {
        if (OUTBF16) {
            uint4 o = make_uint4(pack_bf16x2(acc[0], acc[1]), pack_bf16x2(acc[2], acc[3]),
                                 pack_bf16x2(acc[4], acc[5]), pack_bf16x2(acc[6], acc[7]));
            *(uint4*)((ushort*)outv + (size_t)d * HID + sub * 8) = o;
        } else {
            float* op = (float*)outv + (size_t)d * HID + sub * 8;
            *(float4*)op = make_float4(acc[0], acc[1], acc[2], acc[3]);
            *(float4*)(op + 4) = make_float4(acc[4], acc[5], acc[6], acc[7]);
        }
    }
}

extern "C" void kernel_launch(void* const* d_in, const int* in_sizes, int n_in,
                              void* d_out, int out_size, void* d_ws, size_t ws_size,
                              hipStream_t stream) {
    const float* x  = (const float*)d_in[0];
    const int*   ei = (const int*)d_in[1];
    const float* ew = (const float*)d_in[2];
    const float* W1 = (const float*)d_in[3];
    const float* b1 = (const float*)d_in[4];
    const float* a1 = (const float*)d_in[5];
    const float* W2 = (const float*)d_in[6];
    const float* b2 = (const float*)d_in[7];
    const float* a2 = (const float*)d_in[8];
    float* out = (float*)d_out;

    int N = in_sizes[0] / 256;   // 50000 (fits in 16 bits for edge packing)
    int E = in_sizes[2];         // 800000
    const int* src = ei;
    const int* dst = ei + E;
    int NB = (N + BSZ - 1) >> BSH;   // 782

    // workspace layout
    ushort* fts    = (ushort*)d_ws;                   // N*HID bf16
    ushort* agg    = fts + (size_t)N * HID;           // N*HID bf16
    int2*   staged = (int2*)(agg + (size_t)N * HID);  // E
    int2*   csr    = staged + E;                      // E
    ushort* Wb1    = (ushort*)(csr + E);              // 128*256
    ushort* Wb2    = Wb1 + 128 * 256;                 // 128*128
    int*    ghist  = (int*)(Wb2 + 128 * 128);         // NBMAX
    int*    gbase  = ghist + NBMAX;                   // NBMAX+1
    int*    gcur   = gbase + NBMAX + 1;               // NBMAX
    int*    off    = gcur + NBMAX;                    // N+1

    // ---- W pre-pack + ghist zero (one launch) ----
    w_to_frags_both<<<25, 256, 0, stream>>>(W1, W2, Wb1, Wb2, ghist);

    // ---- two-level CSR build ----
    bucket_hist<<<256, 256, 0, stream>>>(dst, ghist, E, NB);
    bucket_scan<<<1, NBMAX, 0, stream>>>(ghist, gbase, gcur, NB, E);
    bucket_stage<<<128, 256, 0, stream>>>(src, dst, ew, gcur, staged, E, NB);
    node_sort<<<NB, 256, 0, stream>>>(gbase, staged, csr, off, N);

    int gblk = (N + 127) / 128;
    int ggrid = (N + 3) / 4;

    // ---- layer 1 ---- (bias1+PReLU1 fused into gather1 epilogue, bf16 out)
    gemm_mfma<256, false><<<gblk, 256, 0, stream>>>(x, Wb1, fts, N);
    csr_gather_bf16<true><<<ggrid, 256, 0, stream>>>(off, csr, fts, agg, b1, a1, N);

    // ---- layer 2 ---- (A is bf16; bias2+PReLU2 fused into gather2 epilogue)
    gemm_mfma<128, true><<<gblk, 256, 0, stream>>>(agg, Wb2, fts, N);
    csr_gather_bf16<false><<<ggrid, 256, 0, stream>>>(off, csr, fts, out, b2, a2, N);
}